// Round 15
// baseline (325.242 us; speedup 1.0000x reference)
//
#include <hip/hip_runtime.h>

constexpr int kH    = 1024;
constexpr int kNT   = 16384;   // B*S tokens
constexpr int kE    = 4;
constexpr int kC    = 1024;
constexpr int kR    = 4;
constexpr int kKeep = 512;
constexpr float kLoraScale = 0.25f;  // ALPHA / R
constexpr int kCapTiles = 136;
constexpr int kCapRows  = kCapTiles * 128;  // 17408
constexpr int kNRB     = kNT / 128;         // 128 router/slot blocks

// ws layout (float offsets)
constexpr size_t WS_RW     = 0;         // kNT*4 = 65536
constexpr size_t WS_XSUM   = 393216;    // 1024 (region 65536..393216 free)
constexpr size_t WS_SHADOW = 394240;    // 512
constexpr size_t WS_TU     = 394752;    // 32
constexpr size_t WS_VBAR   = 394784;    // 4096
constexpr size_t WS_FX     = 398880;    // 4096 -> 402976
// zero region = [WS_XSUM, 402976) = 9760 floats
constexpr size_t WS_NEWV0  = 402976;    // 4096 -> 407072
constexpr size_t WS_MSK    = 407072;    // 4096 -> 411168
constexpr size_t WS_GBASE  = 411168;    // 8 (int, unused spare)
constexpr size_t WS_BHIST  = 411176;    // 128*6 = 768 (int) -> 411944
constexpr size_t WS_RTPID  = 411944;    // 144 (int) -> 412088
constexpr size_t WS_TPID   = 412088;    // 16384 (int) -> 428472
constexpr size_t WS_GRO    = 428472;    // 16384 (int) -> 444856
constexpr size_t WS_PERM   = 444856;    // 17408 (int) -> 462264
constexpr size_t WS_WCAT   = 462264;    // 20480 -> 482744
constexpr size_t WS_AEXT   = 482744;    // kNT*32 ushort = 262144 fl -> 744888
constexpr size_t WS_AEXTG  = 744888;    // kCapRows*32 ushort = 278528 fl -> 1023416
constexpr size_t WS_BEXT   = 1023416;   // 16384 fl -> 1039800
constexpr size_t WS_WET    = 1039800;   // 2097152 fl -> 3136952
constexpr size_t WS_XG     = 3136952;   // kCapRows*2048 ushort = 17825792 fl
// end = 20962744 floats (~83.9 MB); ws >= 145 MB proven in round 3

// out layout (float offsets)
constexpr size_t OUT_LB = 16777216;
constexpr size_t OUT_NK = 16777217;

typedef __attribute__((ext_vector_type(8))) short bf16x8;
typedef __attribute__((ext_vector_type(4))) float f32x4;

__device__ __forceinline__ float wred(float v) {
#pragma unroll
  for (int off = 32; off; off >>= 1) v += __shfl_xor(v, off);
  return v;
}

__device__ __forceinline__ ushort f2bf(float f) {  // RNE f32 -> bf16
  unsigned int u = __float_as_uint(f);
  u += 0x7FFFu + ((u >> 16) & 1u);
  return (ushort)(u >> 16);
}

__device__ __forceinline__ void gload16(const ushort* g, ushort* l) {
  __builtin_amdgcn_global_load_lds(
      (const __attribute__((address_space(1))) unsigned int*)g,
      (__attribute__((address_space(3))) unsigned int*)l, 16, 0, 0);
}

__device__ __forceinline__ int pid_a(int pid) { return pid < 3 ? 0 : (pid < 5 ? 1 : 2); }
__device__ __forceinline__ int pid_b(int pid) { return pid < 3 ? pid + 1 : (pid < 5 ? pid - 1 : 3); }

// ---- prep: wcat pack (0..79) + keep mask (80..95) + colsum (96..351)
//      + perm init (352..419) ----
__global__ __launch_bounds__(256) void prep_k(
    const float* __restrict__ Wg, const float* __restrict__ Ae,
    const float* __restrict__ ci, const float* __restrict__ x,
    float* __restrict__ wcat, float* __restrict__ msk,
    float* __restrict__ xsum, int* __restrict__ perm) {
  __shared__ float imp[kC];
  const int b = blockIdx.x, tid = threadIdx.x;
  if (b < 80) {
    const int idx = b * 256 + tid;  // 20480
    const int c = idx >> 10, k = idx & 1023;
    float v;
    if (c < 4) v = Wg[(size_t)k * 4 + c];
    else {
      const int e = (c - 4) >> 2, r = (c - 4) & 3;
      v = Ae[((size_t)e * kH + k) * kR + r];
    }
    wcat[(size_t)c * kH + k] = v;
  } else if (b < 96) {
    const int e = (b - 80) >> 2, part = (b - 80) & 3;
    const int c = part * 256 + tid;
    for (int i = tid; i < kC; i += 256) imp[i] = ci[(size_t)e * kC + i];
    __syncthreads();
    const float v = imp[c];
    int rank = 0;
    for (int c2 = 0; c2 < kC; ++c2) {
      const float v2 = imp[c2];
      rank += (v2 > v) || (v2 == v && c2 < c);
    }
    msk[(size_t)e * kC + c] = (rank < kKeep) ? 1.0f : 0.0f;
  } else if (b < 352) {
    const int rg = b - 96;
    const float* xp = x + (size_t)rg * 64 * kH + tid * 4;
    float s0 = 0.f, s1 = 0.f, s2 = 0.f, s3 = 0.f;
    for (int r = 0; r < 64; ++r) {
      const float4 v = *(const float4*)(xp + (size_t)r * kH);
      s0 += v.x; s1 += v.y; s2 += v.z; s3 += v.w;
    }
    atomicAdd(&xsum[tid * 4 + 0], s0);
    atomicAdd(&xsum[tid * 4 + 1], s1);
    atomicAdd(&xsum[tid * 4 + 2], s2);
    atomicAdd(&xsum[tid * 4 + 3], s3);
  } else {
    const int i = (b - 352) * 256 + tid;  // 68*256 = 17408 = kCapRows
    perm[i] = -1;
  }
}

// ---- router GEMM + in-block finalize: rw/pid/aext + lb stats + bhist ----
__global__ __launch_bounds__(256) void rgf_k(
    const float* __restrict__ x, const float* __restrict__ wcat,
    const float* __restrict__ bg, float* __restrict__ rw,
    float* __restrict__ shadow, int* __restrict__ tpid,
    int* __restrict__ bhist, ushort* __restrict__ aext) {
  union Smem {
    float xs[128][64];    // rotation-swizzled float4 slots (K loop)
    float gsh[128][20];   // logits exchange (tail)
  };
  __shared__ Smem sm;
  __shared__ float wt_l[20][64];
  __shared__ float swacc[8];
  __shared__ int ihist[6];
  const int tid = threadIdx.x;
  const int t0 = blockIdx.x * 128;
  const int tok = tid & 127, half = tid >> 7, cb = half * 10;
  const int lane = tid & 63;
  if (tid < 8) swacc[tid] = 0.f;
  if (tid < 6) ihist[tid] = 0;
  float acc[10] = {};
  for (int kc = 0; kc < 16; ++kc) {
#pragma unroll
    for (int i = 0; i < 8; ++i) {
      const int idx = tid + i * 256;
      const int stok = idx >> 4, sslot = idx & 15;
      const float4 v =
          *(const float4*)(x + (size_t)(t0 + stok) * kH + kc * 64 + sslot * 4);
      *(float4*)&sm.xs[stok][((sslot + stok) & 15) * 4] = v;
    }
    for (int idx = tid; idx < 320; idx += 256) {
      const int c = idx >> 4, slot = idx & 15;
      *(float4*)&wt_l[c][slot * 4] =
          *(const float4*)(wcat + (size_t)c * kH + kc * 64 + slot * 4);
    }
    __syncthreads();
#pragma unroll
    for (int k4 = 0; k4 < 16; ++k4) {
      const float4 xv = *(const float4*)&sm.xs[tok][((k4 + tok) & 15) * 4];
#pragma unroll
      for (int j = 0; j < 10; ++j) {
        const float4 wv = *(const float4*)&wt_l[cb + j][k4 * 4];
        acc[j] += xv.x * wv.x + xv.y * wv.y + xv.z * wv.z + xv.w * wv.w;
      }
    }
    __syncthreads();
  }
  // exchange: full 20-vector per token into LDS
#pragma unroll
  for (int j = 0; j < 10; ++j) sm.gsh[tok][cb + j] = acc[j];
  __syncthreads();
  if (tid < 128) {  // waves 0,1 fully active (no intra-wave divergence)
    const int t = t0 + tid;
    float lg[kE];
#pragma unroll
    for (int e = 0; e < kE; ++e) lg[e] = sm.gsh[tid][e] + bg[e];
    float la[kE][kR];
#pragma unroll
    for (int e = 0; e < kE; ++e)
#pragma unroll
      for (int r = 0; r < kR; ++r) la[e][r] = sm.gsh[tid][4 + e * 4 + r];
    const float mx = fmaxf(fmaxf(lg[0], lg[1]), fmaxf(lg[2], lg[3]));
    float ex[kE], se = 0.f;
#pragma unroll
    for (int e = 0; e < kE; ++e) { ex[e] = __expf(lg[e] - mx); se += ex[e]; }
    float pr[kE];
#pragma unroll
    for (int e = 0; e < kE; ++e) pr[e] = ex[e] / se;
    int e1 = 0;
#pragma unroll
    for (int e = 1; e < kE; ++e) if (pr[e] > pr[e1]) e1 = e;
    int e2 = (e1 == 0) ? 1 : 0;
#pragma unroll
    for (int e = 0; e < kE; ++e) if (e != e1 && pr[e] > pr[e2]) e2 = e;
    const float s2 = pr[e1] + pr[e2];
    float rwv[kE] = {0.f, 0.f, 0.f, 0.f};
    rwv[e1] = pr[e1] / s2; rwv[e2] = pr[e2] / s2;
    *(float4*)(rw + (size_t)t * kE) = make_float4(rwv[0], rwv[1], rwv[2], rwv[3]);
    const int lo = min(e1, e2), hi = max(e1, e2);
    const int pid = (lo == 0) ? hi - 1 : ((lo == 1) ? hi + 1 : 5);
    tpid[t] = pid;
    __align__(16) ushort o[32];
#pragma unroll
    for (int e = 0; e < kE; ++e) o[e] = f2bf(rwv[e]);
#pragma unroll
    for (int e = 0; e < kE; ++e)
#pragma unroll
      for (int r = 0; r < kR; ++r)
        o[4 + e * 4 + r] = f2bf(kLoraScale * rwv[e] * la[e][r]);
#pragma unroll
    for (int i = 20; i < 32; ++i) o[i] = 0;
#pragma unroll
    for (int q = 0; q < 4; ++q)
      *(float4*)&aext[(size_t)t * 32 + q * 8] = *(float4*)&o[q * 8];
    float vals[8];
#pragma unroll
    for (int e = 0; e < kE; ++e) {
      vals[e] = pr[e];
      vals[4 + e] = ((e == e1) ? 1.f : 0.f) + ((e == e2) ? 1.f : 0.f);
    }
#pragma unroll
    for (int j = 0; j < 8; ++j) {
      vals[j] = wred(vals[j]);
      if (lane == 0) atomicAdd(&swacc[j], vals[j]);
    }
    atomicAdd(&ihist[pid], 1);
  }
  __syncthreads();
  if (tid < 8) atomicAdd(&shadow[(blockIdx.x & 63) * 8 + tid], swacc[tid]);
  if (tid < 6) bhist[blockIdx.x * 6 + tid] = ihist[tid];
}

// ---- slot: per-block redundant bhist scan + ballot ranking; blk0 -> rtpid ----
__global__ __launch_bounds__(128) void slot_k(const int* __restrict__ tpid,
                                              const int* __restrict__ bhist,
                                              int* __restrict__ gro,
                                              int* __restrict__ perm,
                                              int* __restrict__ rtpid) {
  __shared__ int wcnt[2][6];
  __shared__ int offs[6], totals[6];
  const int tid = threadIdx.x, w = tid >> 6, lane = tid & 63;
  if (tid < 6) {
    int off = 0, tot = 0;
    for (int b2 = 0; b2 < kNRB; ++b2) {
      const int v = bhist[b2 * 6 + tid];
      if (b2 < (int)blockIdx.x) off += v;
      tot += v;
    }
    offs[tid] = off; totals[tid] = tot;
  }
  const int t = blockIdx.x * 128 + tid;
  const int pid = tpid[t];
  unsigned long long mymask = 0;
  int cnt[6];
#pragma unroll
  for (int g = 0; g < 6; ++g) {
    const unsigned long long m = __ballot(pid == g);
    cnt[g] = __popcll(m);
    if (g == pid) mymask = m;
  }
  if (lane < 6) wcnt[w][lane] = cnt[lane];
  const int rank_in_wave =
      __popcll(mymask & ((lane == 63) ? 0x7FFFFFFFFFFFFFFFULL
                                      : ((1ULL << lane) - 1ULL)));
  __syncthreads();
  const int base = (w == 1) ? wcnt[0][pid] : 0;
  int gbase = 0;
  for (int g = 0; g < pid; ++g) gbase += ((totals[g] + 127) >> 7) << 7;
  const int grow = gbase + offs[pid] + base + rank_in_wave;
  gro[t] = grow;
  perm[grow] = t;
  if (blockIdx.x == 0 && tid == 0) {
    int bb = 0;
    for (int g = 0; g < 6; ++g) {
      const int tiles = (totals[g] + 127) >> 7;
      for (int ti = 0; ti < tiles; ++ti) rtpid[(bb >> 7) + ti] = g;
      bb += tiles << 7;
    }
    for (int i = bb >> 7; i < kCapTiles; ++i) rtpid[i] = -1;
  }
}

// ---- aux3: xg gather (0..4095) | wet transpose+fx (4096..5119)
//            | vbar accumulation (5120..5247) ----
__global__ __launch_bounds__(256) void aux3_k(
    const float* __restrict__ x, const float* __restrict__ rw,
    const int* __restrict__ tpid, const ushort* __restrict__ aext,
    const int* __restrict__ gro, ushort* __restrict__ xg,
    ushort* __restrict__ aextg, const float* __restrict__ We,
    const float* __restrict__ xsum, ushort* __restrict__ wet,
    float* __restrict__ fx, const float* __restrict__ cv,
    const float* __restrict__ msk, float* __restrict__ vbar) {
  __shared__ ushort tile[64][72];
  __shared__ float fxl[16][64];
  __shared__ float xml[64];
  const int b = blockIdx.x, tid = threadIdx.x;
  if (b < 4096) {
    // ---- xg gather+prescale, wave-per-token, pure streaming ----
    const int wave = tid >> 6, lane = tid & 63;
    const int t = b * 4 + wave;
    const int pid = tpid[t];
    const int grow = gro[t];
    const float wa = rw[(size_t)t * 4 + pid_a(pid)];
    const float wb = rw[(size_t)t * 4 + pid_b(pid)];
#pragma unroll
    for (int q = 0; q < 4; ++q) {
      const int c = q * 256 + lane * 4;
      const float4 v = *(const float4*)(x + (size_t)t * kH + c);
      ushort4 ua, ub;
      ua.x = f2bf(wa * v.x); ua.y = f2bf(wa * v.y);
      ua.z = f2bf(wa * v.z); ua.w = f2bf(wa * v.w);
      ub.x = f2bf(wb * v.x); ub.y = f2bf(wb * v.y);
      ub.z = f2bf(wb * v.z); ub.w = f2bf(wb * v.w);
      *(ushort4*)(xg + (size_t)grow * 2048 + c) = ua;
      *(ushort4*)(xg + (size_t)grow * 2048 + 1024 + c) = ub;
    }
    if (lane < 4)
      *(float4*)&aextg[(size_t)grow * 32 + lane * 8] =
          *(const float4*)&aext[(size_t)t * 32 + lane * 8];
  } else if (b < 5120) {
    // ---- wet transpose+convert, fused fx partials ----
    const int bp = b - 4096;
    const int jb = bp & 15, kb = (bp >> 4) & 15, e = bp >> 8;
    const int rr = tid >> 4, cq = tid & 15;
    if (tid < 64) xml[tid] = xsum[kb * 64 + tid] * (1.0f / kNT);
    __syncthreads();
    float fxp[4] = {};
#pragma unroll
    for (int p = 0; p < 4; ++p) {
      const int k = kb * 64 + p * 16 + rr;
      const float4 v = *(const float4*)&We[((size_t)e * kH + k) * kH + jb * 64 + cq * 4];
      tile[p * 16 + rr][cq * 4 + 0] = f2bf(v.x);
      tile[p * 16 + rr][cq * 4 + 1] = f2bf(v.y);
      tile[p * 16 + rr][cq * 4 + 2] = f2bf(v.z);
      tile[p * 16 + rr][cq * 4 + 3] = f2bf(v.w);
      const float xm = xml[p * 16 + rr];
      fxp[0] += xm * v.x; fxp[1] += xm * v.y; fxp[2] += xm * v.z; fxp[3] += xm * v.w;
    }
    *(float4*)&fxl[rr][cq * 4] = make_float4(fxp[0], fxp[1], fxp[2], fxp[3]);
    __syncthreads();
    if (tid < 64) {
      float s = 0.f;
#pragma unroll
      for (int r2 = 0; r2 < 16; ++r2) s += fxl[r2][tid];
      atomicAdd(&fx[(size_t)e * kH + jb * 64 + tid], s);
    }
#pragma unroll
    for (int p = 0; p < 4; ++p) {
      const int j = jb * 64 + p * 16 + rr;
      ushort4 u;
      u.x = tile[cq * 4 + 0][p * 16 + rr];
      u.y = tile[cq * 4 + 1][p * 16 + rr];
      u.z = tile[cq * 4 + 2][p * 16 + rr];
      u.w = tile[cq * 4 + 3][p * 16 + rr];
      *(ushort4*)&wet[((size_t)e * kH + j) * kH + kb * 64 + cq * 4] = u;
    }
  } else {
    // ---- vbar accumulation: branchless mask-multiply ----
    const int bp = b - 5120;
    const int e = bp & 3, rc = bp >> 2;
    const float* base = cv + (size_t)e * kC * kH + (size_t)rc * 32 * kH + tid * 4;
    const float* m = msk + (size_t)e * kC + rc * 32;
    float s0 = 0.f, s1 = 0.f, s2 = 0.f, s3 = 0.f;
#pragma unroll 8
    for (int r = 0; r < 32; ++r) {
      const float mr = m[r];
      const float4 v = *(const float4*)(base + (size_t)r * kH);
      s0 += mr * v.x; s1 += mr * v.y; s2 += mr * v.z; s3 += mr * v.w;
    }
    const float sc = 1.0f / kKeep;
    atomicAdd(&vbar[(size_t)e * kH + tid * 4 + 0], s0 * sc);
    atomicAdd(&vbar[(size_t)e * kH + tid * 4 + 1], s1 * sc);
    atomicAdd(&vbar[(size_t)e * kH + tid * 4 + 2], s2 * sc);
    atomicAdd(&vbar[(size_t)e * kH + tid * 4 + 3], s3 * sc);
  }
}

// ---- tu projections + finalize (merged): per-expert block ----
__global__ __launch_bounds__(256) void tufin_k(
    const float* __restrict__ vbar, const float* __restrict__ xsum,
    const float* __restrict__ Av, const float* __restrict__ Ae,
    const float* __restrict__ be, const float* __restrict__ Bv,
    const float* __restrict__ Bee, const float* __restrict__ fx,
    float* __restrict__ newv0_ws, ushort* __restrict__ bext) {
  __shared__ float red[256];
  __shared__ float tus[8];
  const int e = blockIdx.x, tid = threadIdx.x;
  float p[8] = {};
#pragma unroll
  for (int q = 0; q < 4; ++q) {
    const int h = tid * 4 + q;
    const float vb = vbar[(size_t)e * kH + h];
    const float xm = xsum[h] * (1.0f / kNT);
    const float4 av = *(const float4*)(Av + ((size_t)e * kH + h) * kR);
    const float4 ae = *(const float4*)(Ae + ((size_t)e * kH + h) * kR);
    p[0] += vb * av.x; p[1] += vb * av.y; p[2] += vb * av.z; p[3] += vb * av.w;
    p[4] += xm * ae.x; p[5] += xm * ae.y; p[6] += xm * ae.z; p[7] += xm * ae.w;
  }
#pragma unroll
  for (int j = 0; j < 8; ++j) {
    red[tid] = p[j]; __syncthreads();
    for (int s2 = 128; s2; s2 >>= 1) {
      if (tid < s2) red[tid] += red[tid + s2];
      __syncthreads();
    }
    if (tid == 0) tus[j] = red[0];
    __syncthreads();
  }
  float t_[4], u_[4];
#pragma unroll
  for (int r = 0; r < kR; ++r) { t_[r] = tus[r]; u_[r] = tus[4 + r]; }
#pragma unroll
  for (int q = 0; q < 4; ++q) {
    const int col = q * 256 + tid;
    float lv = 0.f, le = 0.f;
#pragma unroll
    for (int r = 0; r < kR; ++r) {
      lv += t_[r] * Bv[((size_t)e * kR + r) * kH + col];
      le += u_[r] * Bee[((size_t)e * kR + r) * kH + col];
    }
    const float mv = vbar[(size_t)e * kH + col] + kLoraScale * lv;
    const float bias = be[(size_t)e * kH + col] + mv;
    newv0_ws[(size_t)e * kH + col] = fx[(size_t)e * kH + col] + kLoraScale * le + bias;
    bext[(size_t)col * 32 + e] = f2bf(bias);
#pragma unroll
    for (int r = 0; r < kR; ++r)
      bext[(size_t)col * 32 + 4 + e * 4 + r] =
          f2bf(Bee[((size_t)e * kR + r) * kH + col]);
    if (e == 0)
#pragma unroll
      for (int i = 20; i < 32; ++i) bext[(size_t)col * 32 + i] = 0;
  }
}

// ---- pair-grouped sparse GEMM (blocks 0..1087) | copyfix (1088+) ----
__global__ __launch_bounds__(256, 2) void gemm_copyfix_k(
    const ushort* __restrict__ xg, const ushort* __restrict__ wet,
    const ushort* __restrict__ aextg, const ushort* __restrict__ bext,
    const int* __restrict__ rtpid, const int* __restrict__ perm,
    const float* __restrict__ ck, const float* __restrict__ cv,
    const float* __restrict__ ci, const float* __restrict__ xsum,
    const float* __restrict__ newv0, const float* __restrict__ shadow,
    float* __restrict__ out) {
  __shared__ __align__(16) ushort As[2][128 * 32];
  __shared__ __align__(16) ushort Bs[2][128 * 32];
  __shared__ int perm_s[128];
  const int tid = threadIdx.x;
  if (blockIdx.x >= 1088) {
    // ---- copyfix: cache copies + row-0 fixes + lb_loss ----
    const size_t NK = (size_t)kE * kC * kH;  // 4194304
    const size_t idx = (size_t)(blockIdx.x - 1088) * 256 + tid;
    if (idx < NK) {
      const size_t c = (idx >> 10) & (kC - 1), h = idx & (kH - 1);
      out[OUT_NK + idx] = (c == 0) ? xsum[h] * (1.0f / kNT) : ck[idx];
    } else if (idx < 2 * NK) {
      const size_t j = idx - NK;
      const size_t e = j >> 20, c = (j >> 10) & (kC - 1), h = j & (kH - 1);
      out[OUT_NK + idx] = (c == 0) ? newv0[e * kH + h] : cv[j];
    } else if (idx < 2 * NK + (size_t)kE * kC) {
      const size_t j = idx - 2 * NK;
      out[OUT_NK + idx] = ((j & (kC - 1)) == 0) ? 1.0f : ci[j];
    } else if (idx == 2 * NK + (size_t)kE * kC) {
      float lb = 0.f;
#pragma unroll
      for (int e = 0; e < kE; ++e) {
        float ps = 0.f, cn = 0.f;
        for (int s2 = 0; s2 < 64; ++s2) {
          ps += shadow[s2 * 8 + e];
          cn += shadow[s2 * 8 + 4 + e];
        }
        lb += (ps * (1.0f / kNT)) * (cn * (1.0f / (kNT * 2.0f)));
      }
      out[OUT_LB] = kE * lb;
    }
    return;
  }
  const int bid = blockIdx.x;                       // 1088 = 8 XCD * 136
  const int gid = (bid & 7) * 136 + (bid >> 3);     // bijective XCD chunking
  const int rt = gid >> 3, ct = gid & 7;            // within XCD: cols fastest
  const int pid = rtpid[rt];
  if (pid < 0) return;
  const int lane = tid & 63, wave = tid >> 6;
  const int wm = wave >> 1, wn = wave & 1;
  const int r0 = rt * 128, c0 = ct * 128;
  const int ea = pid_a(pid), eb = pid_b(pid);
  if (tid < 128) perm_s[tid] = perm[r0 + tid];

  const int srow = lane >> 2;
  const int sslot = lane & 3;

  auto stage = [&](int buf, int kt) {
#pragma unroll
    for (int i = 0; i < 2; ++i) {
      const int j0 = wave * 32 + i * 16;
      const int r = j0 + srow;
      const int slot = sslot ^ ((r >> 1) & 3);
      const ushort* srcA;
      const ushort* srcB;
      if (kt < 64) {
        const int e = (kt < 32) ? ea : eb;
        const int ko = ((kt & 31) * 32) + ((kt < 32) ? 0 : 1024);
        srcA = xg + (size_t)(r0 + r) * 2048 + ko + slot * 8;
        srcB = wet + ((size_t)e * kH + c0 + r) * kH + (kt & 31) * 32 + slot * 8;
      } else {
        srcA = aextg + (size_t)(r0 + r) * 32 + slot * 8;
        srcB = bext + (size_t)(c0 + r) * 32 + slot * 8;
      }
      gload16(srcA, &As[buf][j0 * 32]);
      gload16(srcB, &Bs[buf][j0 * 32]);
    }
  };

  f32x4 acc[4][4] = {};
  stage(0, 0);
  asm volatile("s_waitcnt vmcnt(0)" ::: "memory");
  __syncthreads();

  const int rA = lane & 15;
  const int fslot = lane >> 4;
  int buf = 0;
  for (int kt = 0; kt <= 64; ++kt) {
    if (kt < 64) stage(buf ^ 1, kt + 1);
    bf16x8 a[4], b[4];
#pragma unroll
    for (int m = 0; m < 4; ++m) {
      const int r = wm * 64 + m * 16 + rA;
      const int sl = fslot ^ ((r >> 1) & 3);
      a[m] = *(const bf16x8*)&As[buf][r * 32 + sl * 8];
    }
#pragma unroll
    for (int n = 0; n < 4; ++n) {
      const int r = wn * 64 + n * 16 + rA;
      const int sl = fslot ^ ((r >> 1) & 3);
      b[n] = *(const bf16x8*)&Bs[buf][r * 32 + sl * 8];
    }
#pragma unroll
    for (int m = 0; m < 4; ++m)
#pragma unroll
      for (int n = 0; n < 4; ++n)
        acc[m][n] = __builtin_amdgcn_mfma_f32_16x16x32_bf16(a[m], b[n], acc[m][n], 0, 0, 0);
    if (kt < 64) asm volatile("s_waitcnt vmcnt(0)" ::: "memory");
    __syncthreads();
    buf ^= 1;
  }

#pragma unroll
  for (int m = 0; m < 4; ++m) {
#pragma unroll
    for (int v = 0; v < 4; ++v) {
      const int rl = wm * 64 + m * 16 + (lane >> 4) * 4 + v;
      const int tok = perm_s[rl];
      if (tok >= 0) {
        float* orow = out + (size_t)tok * kH + c0 + wn * 64 + (lane & 15);
#pragma unroll
        for (int n = 0; n < 4; ++n) orow[n * 16] = acc[m][n][v];
      }
    }
  }
}

extern "C" void kernel_launch(void* const* d_in, const int* in_sizes, int n_in,
                              void* d_out, int out_size, void* d_ws, size_t ws_size,
                              hipStream_t stream) {
  const float* x   = (const float*)d_in[0];
  const float* Wg  = (const float*)d_in[2];
  const float* bg  = (const float*)d_in[3];
  const float* We  = (const float*)d_in[12];
  const float* be  = (const float*)d_in[13];
  const float* Ae  = (const float*)d_in[14];
  const float* Bee = (const float*)d_in[15];
  const float* Av  = (const float*)d_in[16];
  const float* Bv  = (const float*)d_in[17];
  const float* ck  = (const float*)d_in[18];
  const float* cv  = (const float*)d_in[19];
  const float* ci  = (const float*)d_in[20];
  float* ws  = (float*)d_ws;
  float* out = (float*)d_out;

  int* tpid  = (int*)(ws + WS_TPID);
  int* bhist = (int*)(ws + WS_BHIST);
  int* rtpid = (int*)(ws + WS_RTPID);
  int* gro   = (int*)(ws + WS_GRO);
  int* perm  = (int*)(ws + WS_PERM);
  ushort* aext  = (ushort*)(ws + WS_AEXT);
  ushort* aextg = (ushort*)(ws + WS_AEXTG);
  ushort* bext  = (ushort*)(ws + WS_BEXT);
  ushort* wet   = (ushort*)(ws + WS_WET);
  ushort* xg    = (ushort*)(ws + WS_XG);

  // zero xsum + shadow + tu + vbar + fx
  hipMemsetAsync(ws + WS_XSUM, 0, 9760 * sizeof(float), stream);
  prep_k<<<420, 256, 0, stream>>>(Wg, Ae, ci, x, ws + WS_WCAT, ws + WS_MSK,
                                  ws + WS_XSUM, perm);
  rgf_k<<<kNRB, 256, 0, stream>>>(x, ws + WS_WCAT, bg, ws + WS_RW,
                                  ws + WS_SHADOW, tpid, bhist, aext);
  slot_k<<<kNRB, 128, 0, stream>>>(tpid, bhist, gro, perm, rtpid);
  aux3_k<<<5248, 256, 0, stream>>>(x, ws + WS_RW, tpid, aext, gro, xg, aextg,
                                   We, ws + WS_XSUM, wet, ws + WS_FX, cv,
                                   ws + WS_MSK, ws + WS_VBAR);
  tufin_k<<<kE, 256, 0, stream>>>(ws + WS_VBAR, ws + WS_XSUM, Av, Ae, be, Bv,
                                  Bee, ws + WS_FX, ws + WS_NEWV0, bext);
  gemm_copyfix_k<<<1088 + 32785, 256, 0, stream>>>(
      xg, wet, aextg, bext, rtpid, perm, ck, cv, ci, ws + WS_XSUM,
      ws + WS_NEWV0, ws + WS_SHADOW, out);
}

// Round 16
// 321.149 us; speedup vs baseline: 1.0127x; 1.0127x over previous
//
#include <hip/hip_runtime.h>

constexpr int kH    = 1024;
constexpr int kNT   = 16384;   // B*S tokens
constexpr int kE    = 4;
constexpr int kC    = 1024;
constexpr int kR    = 4;
constexpr int kKeep = 512;
constexpr float kLoraScale = 0.25f;  // ALPHA / R
constexpr int kCapTiles = 136;
constexpr int kCapRows  = kCapTiles * 128;  // 17408
constexpr int kNB      = kNT / 256;         // 64 token-blocks

// ws layout (float offsets)
constexpr size_t WS_RW     = 0;         // kNT*4 = 65536
constexpr size_t WS_G      = 65536;     // 20*kNT -> 393216
constexpr size_t WS_XSUM   = 393216;    // 1024
constexpr size_t WS_SHADOW = 394240;    // 512
constexpr size_t WS_TU     = 394752;    // 32
constexpr size_t WS_VBAR   = 394784;    // 4096
constexpr size_t WS_FX     = 398880;    // 4096 -> 402976
// zero region = [WS_XSUM, 402976) = 9760 floats
constexpr size_t WS_NEWV0  = 402976;    // 4096 -> 407072
constexpr size_t WS_MSK    = 407072;    // 4096 -> 411168
constexpr size_t WS_GBASE  = 411168;    // 8 (int)
constexpr size_t WS_BHIST  = 411176;    // 64*6 = 384 (int) -> 411560
constexpr size_t WS_BOFF   = 411560;    // 384 (int) -> 411944
constexpr size_t WS_RTPID  = 411944;    // 144 (int) -> 412088
constexpr size_t WS_TPID   = 412088;    // 16384 (int) -> 428472
constexpr size_t WS_GRO    = 428472;    // 16384 (int) -> 444856
constexpr size_t WS_PERM   = 444856;    // 17408 (int) -> 462264
constexpr size_t WS_WCAT   = 462264;    // 20480 -> 482744
constexpr size_t WS_AEXT   = 482744;    // kNT*32 ushort = 262144 fl -> 744888
constexpr size_t WS_AEXTG  = 744888;    // kCapRows*32 ushort = 278528 fl -> 1023416
constexpr size_t WS_BEXT   = 1023416;   // 16384 fl -> 1039800
constexpr size_t WS_WET    = 1039800;   // 2097152 fl -> 3136952
constexpr size_t WS_XG     = 3136952;   // kCapRows*2048 ushort = 17825792 fl
// end = 20962744 floats (~83.9 MB); ws >= 145 MB proven in round 3

// out layout (float offsets)
constexpr size_t OUT_LB = 16777216;
constexpr size_t OUT_NK = 16777217;

typedef __attribute__((ext_vector_type(8))) short bf16x8;
typedef __attribute__((ext_vector_type(4))) float f32x4;

__device__ __forceinline__ float wred(float v) {
#pragma unroll
  for (int off = 32; off; off >>= 1) v += __shfl_xor(v, off);
  return v;
}

__device__ __forceinline__ ushort f2bf(float f) {  // RNE f32 -> bf16
  unsigned int u = __float_as_uint(f);
  u += 0x7FFFu + ((u >> 16) & 1u);
  return (ushort)(u >> 16);
}

__device__ __forceinline__ void gload16(const ushort* g, ushort* l) {
  __builtin_amdgcn_global_load_lds(
      (const __attribute__((address_space(1))) unsigned int*)g,
      (__attribute__((address_space(3))) unsigned int*)l, 16, 0, 0);
}

__device__ __forceinline__ int pid_a(int pid) { return pid < 3 ? 0 : (pid < 5 ? 1 : 2); }
__device__ __forceinline__ int pid_b(int pid) { return pid < 3 ? pid + 1 : (pid < 5 ? pid - 1 : 3); }

// ---- prep: wcat pack (0..79) + keep mask (80..95) + colsum (96..351)
//      + perm init (352..419) ----
__global__ __launch_bounds__(256) void prep_k(
    const float* __restrict__ Wg, const float* __restrict__ Ae,
    const float* __restrict__ ci, const float* __restrict__ x,
    float* __restrict__ wcat, float* __restrict__ msk,
    float* __restrict__ xsum, int* __restrict__ perm) {
  __shared__ float imp[kC];
  const int b = blockIdx.x, tid = threadIdx.x;
  if (b < 80) {
    const int idx = b * 256 + tid;  // 20480
    const int c = idx >> 10, k = idx & 1023;
    float v;
    if (c < 4) v = Wg[(size_t)k * 4 + c];
    else {
      const int e = (c - 4) >> 2, r = (c - 4) & 3;
      v = Ae[((size_t)e * kH + k) * kR + r];
    }
    wcat[(size_t)c * kH + k] = v;
  } else if (b < 96) {
    const int e = (b - 80) >> 2, part = (b - 80) & 3;
    const int c = part * 256 + tid;
    for (int i = tid; i < kC; i += 256) imp[i] = ci[(size_t)e * kC + i];
    __syncthreads();
    const float v = imp[c];
    int rank = 0;
    for (int c2 = 0; c2 < kC; ++c2) {
      const float v2 = imp[c2];
      rank += (v2 > v) || (v2 == v && c2 < c);
    }
    msk[(size_t)e * kC + c] = (rank < kKeep) ? 1.0f : 0.0f;
  } else if (b < 352) {
    const int rg = b - 96;
    const float* xp = x + (size_t)rg * 64 * kH + tid * 4;
    float s0 = 0.f, s1 = 0.f, s2 = 0.f, s3 = 0.f;
    for (int r = 0; r < 64; ++r) {
      const float4 v = *(const float4*)(xp + (size_t)r * kH);
      s0 += v.x; s1 += v.y; s2 += v.z; s3 += v.w;
    }
    atomicAdd(&xsum[tid * 4 + 0], s0);
    atomicAdd(&xsum[tid * 4 + 1], s1);
    atomicAdd(&xsum[tid * 4 + 2], s2);
    atomicAdd(&xsum[tid * 4 + 3], s3);
  } else {
    const int i = (b - 352) * 256 + tid;  // 68*256 = 17408 = kCapRows
    perm[i] = -1;
  }
}

// ---- router GEMM: G[c][t] = sum_k x[t][k] * Wcat[c][k]  (c = 20) ----
__global__ __launch_bounds__(256) void router_gemm_k(
    const float* __restrict__ x, const float* __restrict__ wcat,
    float* __restrict__ G) {
  __shared__ float xs_l[128][64];   // rotation-swizzled float4 slots
  __shared__ float wt_l[20][64];
  const int tid = threadIdx.x;
  const int t0 = blockIdx.x * 128;
  const int tok = tid & 127, half = tid >> 7, cb = half * 10;
  float acc[10] = {};
  for (int kc = 0; kc < 16; ++kc) {
#pragma unroll
    for (int i = 0; i < 8; ++i) {
      const int idx = tid + i * 256;
      const int stok = idx >> 4, sslot = idx & 15;
      const float4 v =
          *(const float4*)(x + (size_t)(t0 + stok) * kH + kc * 64 + sslot * 4);
      *(float4*)&xs_l[stok][((sslot + stok) & 15) * 4] = v;
    }
    for (int idx = tid; idx < 320; idx += 256) {
      const int c = idx >> 4, slot = idx & 15;
      *(float4*)&wt_l[c][slot * 4] =
          *(const float4*)(wcat + (size_t)c * kH + kc * 64 + slot * 4);
    }
    __syncthreads();
#pragma unroll
    for (int k4 = 0; k4 < 16; ++k4) {
      const float4 xv = *(const float4*)&xs_l[tok][((k4 + tok) & 15) * 4];
#pragma unroll
      for (int j = 0; j < 10; ++j) {
        const float4 wv = *(const float4*)&wt_l[cb + j][k4 * 4];
        acc[j] += xv.x * wv.x + xv.y * wv.y + xv.z * wv.z + xv.w * wv.w;
      }
    }
    __syncthreads();
  }
#pragma unroll
  for (int j = 0; j < 10; ++j)
    G[(size_t)(cb + j) * kNT + t0 + tok] = acc[j];
}

// ---- router finalize: softmax/top2/rw/pid/aext + lb stats + block hist ----
__global__ __launch_bounds__(256) void router_fin_k(
    const float* __restrict__ G, const float* __restrict__ bg,
    float* __restrict__ rw, float* __restrict__ shadow,
    int* __restrict__ tpid, int* __restrict__ bhist,
    ushort* __restrict__ aext) {
  __shared__ float swacc[8];
  __shared__ int ihist[6];
  const int tid = threadIdx.x;
  const int t = blockIdx.x * 256 + tid;
  const int lane = tid & 63;
  if (tid < 8) swacc[tid] = 0.f;
  if (tid < 6) ihist[tid] = 0;
  __syncthreads();
  float lg[kE];
#pragma unroll
  for (int e = 0; e < kE; ++e) lg[e] = G[(size_t)e * kNT + t] + bg[e];
  float la[kE][kR];
#pragma unroll
  for (int e = 0; e < kE; ++e)
#pragma unroll
    for (int r = 0; r < kR; ++r)
      la[e][r] = G[(size_t)(4 + e * 4 + r) * kNT + t];
  const float mx = fmaxf(fmaxf(lg[0], lg[1]), fmaxf(lg[2], lg[3]));
  float ex[kE], se = 0.f;
#pragma unroll
  for (int e = 0; e < kE; ++e) { ex[e] = __expf(lg[e] - mx); se += ex[e]; }
  float pr[kE];
#pragma unroll
  for (int e = 0; e < kE; ++e) pr[e] = ex[e] / se;
  int e1 = 0;
#pragma unroll
  for (int e = 1; e < kE; ++e) if (pr[e] > pr[e1]) e1 = e;
  int e2 = (e1 == 0) ? 1 : 0;
#pragma unroll
  for (int e = 0; e < kE; ++e) if (e != e1 && pr[e] > pr[e2]) e2 = e;
  const float s2 = pr[e1] + pr[e2];
  float rwv[kE] = {0.f, 0.f, 0.f, 0.f};
  rwv[e1] = pr[e1] / s2; rwv[e2] = pr[e2] / s2;
  *(float4*)(rw + (size_t)t * kE) = make_float4(rwv[0], rwv[1], rwv[2], rwv[3]);
  const int lo = min(e1, e2), hi = max(e1, e2);
  const int pid = (lo == 0) ? hi - 1 : ((lo == 1) ? hi + 1 : 5);
  tpid[t] = pid;
  __align__(16) ushort o[32];
#pragma unroll
  for (int e = 0; e < kE; ++e) o[e] = f2bf(rwv[e]);
#pragma unroll
  for (int e = 0; e < kE; ++e)
#pragma unroll
    for (int r = 0; r < kR; ++r)
      o[4 + e * 4 + r] = f2bf(kLoraScale * rwv[e] * la[e][r]);
#pragma unroll
  for (int i = 20; i < 32; ++i) o[i] = 0;
#pragma unroll
  for (int q = 0; q < 4; ++q)
    *(float4*)&aext[(size_t)t * 32 + q * 8] = *(float4*)&o[q * 8];
  // lb stats: wave-reduce, aggregate in LDS, one atomic per block
  float vals[8];
#pragma unroll
  for (int e = 0; e < kE; ++e) {
    vals[e] = pr[e];
    vals[4 + e] = ((e == e1) ? 1.f : 0.f) + ((e == e2) ? 1.f : 0.f);
  }
#pragma unroll
  for (int j = 0; j < 8; ++j) {
    vals[j] = wred(vals[j]);
    if (lane == 0) atomicAdd(&swacc[j], vals[j]);
  }
  atomicAdd(&ihist[pid], 1);
  __syncthreads();
  if (tid < 8) atomicAdd(&shadow[(blockIdx.x & 63) * 8 + tid], swacc[tid]);
  if (tid < 6) bhist[blockIdx.x * 6 + tid] = ihist[tid];
}

// ---- 1-block scan: pcnt from bhist, 128-aligned bases, boff, rtpid ----
__global__ __launch_bounds__(256) void pscan_k(const int* __restrict__ bhist,
                                               int* __restrict__ gbase,
                                               int* __restrict__ boff,
                                               int* __restrict__ rtpid) {
  __shared__ int pcnt_s[6];
  const int tid = threadIdx.x;
  if (tid < 6) {
    int run = 0;
    for (int b = 0; b < kNB; ++b) {
      boff[b * 6 + tid] = run;
      run += bhist[b * 6 + tid];
    }
    pcnt_s[tid] = run;
  }
  __syncthreads();
  if (tid == 0) {
    int base = 0;
    for (int g = 0; g < 6; ++g) {
      gbase[g] = base;
      const int tiles = (pcnt_s[g] + 127) >> 7;
      for (int ti = 0; ti < tiles; ++ti) rtpid[(base >> 7) + ti] = g;
      base += tiles << 7;
    }
    for (int i = base >> 7; i < kCapTiles; ++i) rtpid[i] = -1;
  }
  __syncthreads();
  if (tid < 6) {
    const int gb = gbase[tid];
    for (int b = 0; b < kNB; ++b) boff[b * 6 + tid] += gb;
  }
}

// ---- slot assignment: deterministic rank via ballots (no atomics) ----
__global__ __launch_bounds__(256) void slot_k(const int* __restrict__ tpid,
                                              const int* __restrict__ boff,
                                              int* __restrict__ gro,
                                              int* __restrict__ perm) {
  __shared__ int wcnt[4][6];
  const int tid = threadIdx.x, w = tid >> 6, lane = tid & 63;
  const int t = blockIdx.x * 256 + tid;
  const int pid = tpid[t];
  unsigned long long mymask = 0;
  int cnt[6];
#pragma unroll
  for (int g = 0; g < 6; ++g) {
    const unsigned long long m = __ballot(pid == g);
    cnt[g] = __popcll(m);
    if (g == pid) mymask = m;
  }
  if (lane < 6) wcnt[w][lane] = cnt[lane];
  const int rank_in_wave =
      __popcll(mymask & ((lane == 63) ? 0x7FFFFFFFFFFFFFFFULL
                                      : ((1ULL << lane) - 1ULL)));
  __syncthreads();
  int base = 0;
  for (int w2 = 0; w2 < w; ++w2) base += wcnt[w2][pid];
  const int grow = boff[blockIdx.x * 6 + pid] + base + rank_in_wave;
  gro[t] = grow;
  perm[grow] = t;
}

// ---- aux3: xg gather (0..4095) | wet transpose+fx (4096..5119)
//            | vbar accumulation (5120..5247) ----
__global__ __launch_bounds__(256) void aux3_k(
    const float* __restrict__ x, const float* __restrict__ rw,
    const int* __restrict__ tpid, const ushort* __restrict__ aext,
    const int* __restrict__ gro, ushort* __restrict__ xg,
    ushort* __restrict__ aextg, const float* __restrict__ We,
    const float* __restrict__ xsum, ushort* __restrict__ wet,
    float* __restrict__ fx, const float* __restrict__ cv,
    const float* __restrict__ msk, float* __restrict__ vbar) {
  __shared__ ushort tile[64][72];
  __shared__ float fxl[16][64];
  __shared__ float xml[64];
  const int b = blockIdx.x, tid = threadIdx.x;
  if (b < 4096) {
    // ---- xg gather+prescale, wave-per-token, pure streaming ----
    const int wave = tid >> 6, lane = tid & 63;
    const int t = b * 4 + wave;
    const int pid = tpid[t];
    const int grow = gro[t];
    const float wa = rw[(size_t)t * 4 + pid_a(pid)];
    const float wb = rw[(size_t)t * 4 + pid_b(pid)];
#pragma unroll
    for (int q = 0; q < 4; ++q) {
      const int c = q * 256 + lane * 4;
      const float4 v = *(const float4*)(x + (size_t)t * kH + c);
      ushort4 ua, ub;
      ua.x = f2bf(wa * v.x); ua.y = f2bf(wa * v.y);
      ua.z = f2bf(wa * v.z); ua.w = f2bf(wa * v.w);
      ub.x = f2bf(wb * v.x); ub.y = f2bf(wb * v.y);
      ub.z = f2bf(wb * v.z); ub.w = f2bf(wb * v.w);
      *(ushort4*)(xg + (size_t)grow * 2048 + c) = ua;
      *(ushort4*)(xg + (size_t)grow * 2048 + 1024 + c) = ub;
    }
    if (lane < 4)
      *(float4*)&aextg[(size_t)grow * 32 + lane * 8] =
          *(const float4*)&aext[(size_t)t * 32 + lane * 8];
  } else if (b < 5120) {
    // ---- wet transpose+convert, fused fx partials ----
    const int bp = b - 4096;
    const int jb = bp & 15, kb = (bp >> 4) & 15, e = bp >> 8;
    const int rr = tid >> 4, cq = tid & 15;
    if (tid < 64) xml[tid] = xsum[kb * 64 + tid] * (1.0f / kNT);
    __syncthreads();
    float fxp[4] = {};
#pragma unroll
    for (int p = 0; p < 4; ++p) {
      const int k = kb * 64 + p * 16 + rr;
      const float4 v = *(const float4*)&We[((size_t)e * kH + k) * kH + jb * 64 + cq * 4];
      tile[p * 16 + rr][cq * 4 + 0] = f2bf(v.x);
      tile[p * 16 + rr][cq * 4 + 1] = f2bf(v.y);
      tile[p * 16 + rr][cq * 4 + 2] = f2bf(v.z);
      tile[p * 16 + rr][cq * 4 + 3] = f2bf(v.w);
      const float xm = xml[p * 16 + rr];
      fxp[0] += xm * v.x; fxp[1] += xm * v.y; fxp[2] += xm * v.z; fxp[3] += xm * v.w;
    }
    *(float4*)&fxl[rr][cq * 4] = make_float4(fxp[0], fxp[1], fxp[2], fxp[3]);
    __syncthreads();
    if (tid < 64) {
      float s = 0.f;
#pragma unroll
      for (int r2 = 0; r2 < 16; ++r2) s += fxl[r2][tid];
      atomicAdd(&fx[(size_t)e * kH + jb * 64 + tid], s);
    }
#pragma unroll
    for (int p = 0; p < 4; ++p) {
      const int j = jb * 64 + p * 16 + rr;
      ushort4 u;
      u.x = tile[cq * 4 + 0][p * 16 + rr];
      u.y = tile[cq * 4 + 1][p * 16 + rr];
      u.z = tile[cq * 4 + 2][p * 16 + rr];
      u.w = tile[cq * 4 + 3][p * 16 + rr];
      *(ushort4*)&wet[((size_t)e * kH + j) * kH + kb * 64 + cq * 4] = u;
    }
  } else {
    // ---- vbar accumulation: branchless mask-multiply ----
    const int bp = b - 5120;
    const int e = bp & 3, rc = bp >> 2;
    const float* base = cv + (size_t)e * kC * kH + (size_t)rc * 32 * kH + tid * 4;
    const float* m = msk + (size_t)e * kC + rc * 32;
    float s0 = 0.f, s1 = 0.f, s2 = 0.f, s3 = 0.f;
#pragma unroll 8
    for (int r = 0; r < 32; ++r) {
      const float mr = m[r];
      const float4 v = *(const float4*)(base + (size_t)r * kH);
      s0 += mr * v.x; s1 += mr * v.y; s2 += mr * v.z; s3 += mr * v.w;
    }
    const float sc = 1.0f / kKeep;
    atomicAdd(&vbar[(size_t)e * kH + tid * 4 + 0], s0 * sc);
    atomicAdd(&vbar[(size_t)e * kH + tid * 4 + 1], s1 * sc);
    atomicAdd(&vbar[(size_t)e * kH + tid * 4 + 2], s2 * sc);
    atomicAdd(&vbar[(size_t)e * kH + tid * 4 + 3], s3 * sc);
  }
}

// ---- tu projections + finalize (merged): per-expert block ----
__global__ __launch_bounds__(256) void tufin_k(
    const float* __restrict__ vbar, const float* __restrict__ xsum,
    const float* __restrict__ Av, const float* __restrict__ Ae,
    const float* __restrict__ be, const float* __restrict__ Bv,
    const float* __restrict__ Bee, const float* __restrict__ fx,
    float* __restrict__ newv0_ws, ushort* __restrict__ bext) {
  __shared__ float red[256];
  __shared__ float tus[8];
  const int e = blockIdx.x, tid = threadIdx.x;
  float p[8] = {};
#pragma unroll
  for (int q = 0; q < 4; ++q) {
    const int h = tid * 4 + q;
    const float vb = vbar[(size_t)e * kH + h];
    const float xm = xsum[h] * (1.0f / kNT);
    const float4 av = *(const float4*)(Av + ((size_t)e * kH + h) * kR);
    const float4 ae = *(const float4*)(Ae + ((size_t)e * kH + h) * kR);
    p[0] += vb * av.x; p[1] += vb * av.y; p[2] += vb * av.z; p[3] += vb * av.w;
    p[4] += xm * ae.x; p[5] += xm * ae.y; p[6] += xm * ae.z; p[7] += xm * ae.w;
  }
#pragma unroll
  for (int j = 0; j < 8; ++j) {
    red[tid] = p[j]; __syncthreads();
    for (int s2 = 128; s2; s2 >>= 1) {
      if (tid < s2) red[tid] += red[tid + s2];
      __syncthreads();
    }
    if (tid == 0) tus[j] = red[0];
    __syncthreads();
  }
  float t_[4], u_[4];
#pragma unroll
  for (int r = 0; r < kR; ++r) { t_[r] = tus[r]; u_[r] = tus[4 + r]; }
#pragma unroll
  for (int q = 0; q < 4; ++q) {
    const int col = q * 256 + tid;
    float lv = 0.f, le = 0.f;
#pragma unroll
    for (int r = 0; r < kR; ++r) {
      lv += t_[r] * Bv[((size_t)e * kR + r) * kH + col];
      le += u_[r] * Bee[((size_t)e * kR + r) * kH + col];
    }
    const float mv = vbar[(size_t)e * kH + col] + kLoraScale * lv;
    const float bias = be[(size_t)e * kH + col] + mv;
    newv0_ws[(size_t)e * kH + col] = fx[(size_t)e * kH + col] + kLoraScale * le + bias;
    bext[(size_t)col * 32 + e] = f2bf(bias);
#pragma unroll
    for (int r = 0; r < kR; ++r)
      bext[(size_t)col * 32 + 4 + e * 4 + r] =
          f2bf(Bee[((size_t)e * kR + r) * kH + col]);
    if (e == 0)
#pragma unroll
      for (int i = 20; i < 32; ++i) bext[(size_t)col * 32 + i] = 0;
  }
}

// ---- pair-grouped sparse GEMM (blocks 0..1087) | copyfix (1088+) ----
__global__ __launch_bounds__(256, 2) void gemm_copyfix_k(
    const ushort* __restrict__ xg, const ushort* __restrict__ wet,
    const ushort* __restrict__ aextg, const ushort* __restrict__ bext,
    const int* __restrict__ rtpid, const int* __restrict__ perm,
    const float* __restrict__ ck, const float* __restrict__ cv,
    const float* __restrict__ ci, const float* __restrict__ xsum,
    const float* __restrict__ newv0, const float* __restrict__ shadow,
    float* __restrict__ out) {
  __shared__ __align__(16) ushort As[2][128 * 32];
  __shared__ __align__(16) ushort Bs[2][128 * 32];
  __shared__ int perm_s[128];
  const int tid = threadIdx.x;
  if (blockIdx.x >= 1088) {
    // ---- copyfix: cache copies + row-0 fixes + lb_loss ----
    const size_t NK = (size_t)kE * kC * kH;  // 4194304
    const size_t idx = (size_t)(blockIdx.x - 1088) * 256 + tid;
    if (idx < NK) {
      const size_t c = (idx >> 10) & (kC - 1), h = idx & (kH - 1);
      out[OUT_NK + idx] = (c == 0) ? xsum[h] * (1.0f / kNT) : ck[idx];
    } else if (idx < 2 * NK) {
      const size_t j = idx - NK;
      const size_t e = j >> 20, c = (j >> 10) & (kC - 1), h = j & (kH - 1);
      out[OUT_NK + idx] = (c == 0) ? newv0[e * kH + h] : cv[j];
    } else if (idx < 2 * NK + (size_t)kE * kC) {
      const size_t j = idx - 2 * NK;
      out[OUT_NK + idx] = ((j & (kC - 1)) == 0) ? 1.0f : ci[j];
    } else if (idx == 2 * NK + (size_t)kE * kC) {
      float lb = 0.f;
#pragma unroll
      for (int e = 0; e < kE; ++e) {
        float ps = 0.f, cn = 0.f;
        for (int s2 = 0; s2 < 64; ++s2) {
          ps += shadow[s2 * 8 + e];
          cn += shadow[s2 * 8 + 4 + e];
        }
        lb += (ps * (1.0f / kNT)) * (cn * (1.0f / (kNT * 2.0f)));
      }
      out[OUT_LB] = kE * lb;
    }
    return;
  }
  const int bid = blockIdx.x;                       // 1088 = 8 XCD * 136
  const int gid = (bid & 7) * 136 + (bid >> 3);     // bijective XCD chunking
  const int rt = gid >> 3, ct = gid & 7;            // within XCD: cols fastest
  const int pid = rtpid[rt];
  if (pid < 0) return;
  const int lane = tid & 63, wave = tid >> 6;
  const int wm = wave >> 1, wn = wave & 1;
  const int r0 = rt * 128, c0 = ct * 128;
  const int ea = pid_a(pid), eb = pid_b(pid);
  if (tid < 128) perm_s[tid] = perm[r0 + tid];

  const int srow = lane >> 2;
  const int sslot = lane & 3;

  auto stage = [&](int buf, int kt) {
#pragma unroll
    for (int i = 0; i < 2; ++i) {
      const int j0 = wave * 32 + i * 16;
      const int r = j0 + srow;
      const int slot = sslot ^ ((r >> 1) & 3);
      const ushort* srcA;
      const ushort* srcB;
      if (kt < 64) {
        const int e = (kt < 32) ? ea : eb;
        const int ko = ((kt & 31) * 32) + ((kt < 32) ? 0 : 1024);
        srcA = xg + (size_t)(r0 + r) * 2048 + ko + slot * 8;
        srcB = wet + ((size_t)e * kH + c0 + r) * kH + (kt & 31) * 32 + slot * 8;
      } else {
        srcA = aextg + (size_t)(r0 + r) * 32 + slot * 8;
        srcB = bext + (size_t)(c0 + r) * 32 + slot * 8;
      }
      gload16(srcA, &As[buf][j0 * 32]);
      gload16(srcB, &Bs[buf][j0 * 32]);
    }
  };

  f32x4 acc[4][4] = {};
  stage(0, 0);
  asm volatile("s_waitcnt vmcnt(0)" ::: "memory");
  __syncthreads();

  const int rA = lane & 15;
  const int fslot = lane >> 4;
  int buf = 0;
  for (int kt = 0; kt <= 64; ++kt) {
    if (kt < 64) stage(buf ^ 1, kt + 1);
    bf16x8 a[4], b[4];
#pragma unroll
    for (int m = 0; m < 4; ++m) {
      const int r = wm * 64 + m * 16 + rA;
      const int sl = fslot ^ ((r >> 1) & 3);
      a[m] = *(const bf16x8*)&As[buf][r * 32 + sl * 8];
    }
#pragma unroll
    for (int n = 0; n < 4; ++n) {
      const int r = wn * 64 + n * 16 + rA;
      const int sl = fslot ^ ((r >> 1) & 3);
      b[n] = *(const bf16x8*)&Bs[buf][r * 32 + sl * 8];
    }
#pragma unroll
    for (int m = 0; m < 4; ++m)
#pragma unroll
      for (int n = 0; n < 4; ++n)
        acc[m][n] = __builtin_amdgcn_mfma_f32_16x16x32_bf16(a[m], b[n], acc[m][n], 0, 0, 0);
    if (kt < 64) asm volatile("s_waitcnt vmcnt(0)" ::: "memory");
    __syncthreads();
    buf ^= 1;
  }

#pragma unroll
  for (int m = 0; m < 4; ++m) {
#pragma unroll
    for (int v = 0; v < 4; ++v) {
      const int rl = wm * 64 + m * 16 + (lane >> 4) * 4 + v;
      const int tok = perm_s[rl];
      if (tok >= 0) {
        float* orow = out + (size_t)tok * kH + c0 + wn * 64 + (lane & 15);
#pragma unroll
        for (int n = 0; n < 4; ++n) orow[n * 16] = acc[m][n][v];
      }
    }
  }
}

extern "C" void kernel_launch(void* const* d_in, const int* in_sizes, int n_in,
                              void* d_out, int out_size, void* d_ws, size_t ws_size,
                              hipStream_t stream) {
  const float* x   = (const float*)d_in[0];
  const float* Wg  = (const float*)d_in[2];
  const float* bg  = (const float*)d_in[3];
  const float* We  = (const float*)d_in[12];
  const float* be  = (const float*)d_in[13];
  const float* Ae  = (const float*)d_in[14];
  const float* Bee = (const float*)d_in[15];
  const float* Av  = (const float*)d_in[16];
  const float* Bv  = (const float*)d_in[17];
  const float* ck  = (const float*)d_in[18];
  const float* cv  = (const float*)d_in[19];
  const float* ci  = (const float*)d_in[20];
  float* ws  = (float*)d_ws;
  float* out = (float*)d_out;

  int* tpid  = (int*)(ws + WS_TPID);
  int* bhist = (int*)(ws + WS_BHIST);
  int* boff  = (int*)(ws + WS_BOFF);
  int* gbase = (int*)(ws + WS_GBASE);
  int* rtpid = (int*)(ws + WS_RTPID);
  int* gro   = (int*)(ws + WS_GRO);
  int* perm  = (int*)(ws + WS_PERM);
  ushort* aext  = (ushort*)(ws + WS_AEXT);
  ushort* aextg = (ushort*)(ws + WS_AEXTG);
  ushort* bext  = (ushort*)(ws + WS_BEXT);
  ushort* wet   = (ushort*)(ws + WS_WET);
  ushort* xg    = (ushort*)(ws + WS_XG);

  // zero xsum + shadow + tu + vbar + fx
  hipMemsetAsync(ws + WS_XSUM, 0, 9760 * sizeof(float), stream);
  prep_k<<<420, 256, 0, stream>>>(Wg, Ae, ci, x, ws + WS_WCAT, ws + WS_MSK,
                                  ws + WS_XSUM, perm);
  router_gemm_k<<<kNT / 128, 256, 0, stream>>>(x, ws + WS_WCAT, ws + WS_G);
  router_fin_k<<<kNB, 256, 0, stream>>>(ws + WS_G, bg, ws + WS_RW,
                                        ws + WS_SHADOW, tpid, bhist, aext);
  pscan_k<<<1, 256, 0, stream>>>(bhist, gbase, boff, rtpid);
  slot_k<<<kNB, 256, 0, stream>>>(tpid, boff, gro, perm);
  aux3_k<<<5248, 256, 0, stream>>>(x, ws + WS_RW, tpid, aext, gro, xg, aextg,
                                   We, ws + WS_XSUM, wet, ws + WS_FX, cv,
                                   ws + WS_MSK, ws + WS_VBAR);
  tufin_k<<<kE, 256, 0, stream>>>(ws + WS_VBAR, ws + WS_XSUM, Av, Ae, be, Bv,
                                  Bee, ws + WS_FX, ws + WS_NEWV0, bext);
  gemm_copyfix_k<<<1088 + 32785, 256, 0, stream>>>(
      xg, wet, aextg, bext, rtpid, perm, ck, cv, ci, ws + WS_XSUM,
      ws + WS_NEWV0, ws + WS_SHADOW, out);
}